// Round 1
// 137.930 us; speedup vs baseline: 1.0212x; 1.0212x over previous
//
#include <hip/hip_runtime.h>

#define SEQ 4096
#define DIM 64
#define CHUNK 128
#define NC 32
#define EPSV 1e-10f
#define KS_OFF 2097152   // float offset of ksum region (S region = 1024 chunks * 4096 bf16 = 8 MiB)

typedef __attribute__((ext_vector_type(8))) short s16x8;   // 8 bf16 (4 VGPRs)
typedef __attribute__((ext_vector_type(4))) float f32x4;   // MFMA C/D

__device__ __forceinline__ unsigned short f2bf(float f) {
  unsigned int u = __float_as_uint(f);
  u += 0x7FFF + ((u >> 16) & 1);          // RNE (inputs are finite)
  return (unsigned short)(u >> 16);
}
__device__ __forceinline__ s16x8 pack8(float4 a, float4 b) {
  s16x8 r;
  r[0] = (short)f2bf(a.x); r[1] = (short)f2bf(a.y); r[2] = (short)f2bf(a.z); r[3] = (short)f2bf(a.w);
  r[4] = (short)f2bf(b.x); r[5] = (short)f2bf(b.y); r[6] = (short)f2bf(b.z); r[7] = (short)f2bf(b.w);
  return r;
}

// Coalesced transposed gather: global [128][64] f32 row-major -> LDS T[d][j] bf16, stride 136.
// DIM==64 => lane d reads 64 consecutive dwords per instruction (perfect coalescing).
// Optionally accumulates the fp32 column sum (sum over this thread's 32 j's at its fixed d).
template<bool SUM>
__device__ __forceinline__ float gather_T(const float* __restrict__ gp,
                                          unsigned short* __restrict__ dst, int t) {
  int d = t & 63, w6 = t >> 6;
  float s = 0.f;
#pragma unroll
  for (int i = 0; i < 4; ++i) {
    int j8 = w6 + i * 4;                          // fixed d, 4 j8-groups per thread
    const float* p = gp + (size_t)(j8 * 8) * DIM + d;
    float x[8];
#pragma unroll
    for (int u = 0; u < 8; ++u) x[u] = p[(size_t)u * DIM];
    if (SUM) {
#pragma unroll
      for (int u = 0; u < 8; ++u) s += x[u];
    }
    s16x8 seg;
#pragma unroll
    for (int u = 0; u < 8; ++u) seg[u] = (short)f2bf(x[u]);
    *(s16x8*)&dst[d * 136 + j8 * 8] = seg;
  }
  return s;
}

// ---------------- Pass A: S^T[e][d] = sum_j v[j][e] k[j][d] via MFMA; store bf16 ----------------
__global__ __launch_bounds__(256) void pass_a(const float* __restrict__ k0,
                                              const float* __restrict__ k1,
                                              const float* __restrict__ v,
                                              float* __restrict__ ws) {
  __shared__ __align__(16) unsigned short skT[64 * 136];   // kT[d][j]
  __shared__ __align__(16) unsigned short svT[64 * 136];   // vT[e][j]
  __shared__ float spart[4][64];                           // fp32 ksum partials
  int bid = blockIdx.x;
  int m = bid >> 9, rem = bid & 511, hh = rem >> 5, c = rem & 31;
  const float* kp = (m ? k1 : k0) + (size_t)hh * SEQ * DIM + (size_t)c * CHUNK * DIM;
  const float* vp = v + (size_t)hh * SEQ * DIM + (size_t)c * CHUNK * DIM;
  int t = threadIdx.x;

  float s = gather_T<true>(kp, skT, t);
  gather_T<false>(vp, svT, t);
  spart[t >> 6][t & 63] = s;
  __syncthreads();

  // ksum[d] in full fp32 (pre-rounding values)
  if (t < 64)
    ws[KS_OFF + (size_t)bid * 64 + t] = spart[0][t] + spart[1][t] + spart[2][t] + spart[3][t];

  // MFMA: wave w -> e-tile w; A = vT (m=e), B = kT rows (k=j, n=d)
  int w = t >> 6, L = t & 63, g = L >> 4, cL = L & 15;
  f32x4 acc[4];
#pragma unroll
  for (int ct = 0; ct < 4; ++ct) acc[ct] = (f32x4){0.f, 0.f, 0.f, 0.f};
#pragma unroll
  for (int ks = 0; ks < 4; ++ks) {
    s16x8 aF = *(const s16x8*)&svT[(w * 16 + cL) * 136 + ks * 32 + g * 8];
#pragma unroll
    for (int ct = 0; ct < 4; ++ct) {
      s16x8 bF = *(const s16x8*)&skT[(ct * 16 + cL) * 136 + ks * 32 + g * 8];
      acc[ct] = __builtin_amdgcn_mfma_f32_16x16x32_bf16(aF, bF, acc[ct], 0, 0, 0);
    }
  }
  // C/D layout: col = cL (=d-local), row = g*4+r (=e-local); store bf16
  unsigned short* Sp = (unsigned short*)ws + (size_t)bid * 4096;
#pragma unroll
  for (int ct = 0; ct < 4; ++ct)
#pragma unroll
    for (int r = 0; r < 4; ++r)
      Sp[(size_t)(w * 16 + g * 4 + r) * 64 + ct * 16 + cL] = f2bf(acc[ct][r]);
}

// ---------------- Pass B: exclusive prefix over chunks; all 32 loads in flight ----------------
// Blocks 0..255: S region (u32 = 2 bf16 lanes). Blocks 256..263: ksum (fp32).
__global__ __launch_bounds__(256) void pass_b(float* __restrict__ ws) {
  int t = threadIdx.x;
  if (blockIdx.x < 256) {
    int gid = blockIdx.x * 256 + t;            // [0, 65536)
    int mh = gid >> 11, de2 = gid & 2047;      // mh in [0,32)
    unsigned int* p = (unsigned int*)ws + (size_t)mh * NC * 2048 + de2;
    unsigned int x[NC];
#pragma unroll
    for (int c = 0; c < NC; ++c) x[c] = p[(size_t)c * 2048];
    float r0 = 0.f, r1 = 0.f;
#pragma unroll
    for (int c = 0; c < NC; ++c) {
      unsigned int xc = x[c];
      p[(size_t)c * 2048] = (unsigned int)f2bf(r0) | ((unsigned int)f2bf(r1) << 16);
      r0 += __uint_as_float((xc & 0xFFFFu) << 16);
      r1 += __uint_as_float(xc & 0xFFFF0000u);
    }
  } else {
    int gid = (blockIdx.x - 256) * 256 + t;    // [0, 2048)
    int mh = gid >> 6, d = gid & 63;
    float* p = ws + KS_OFF + (size_t)mh * NC * 64 + d;
    float x[NC];
#pragma unroll
    for (int c = 0; c < NC; ++c) x[c] = p[(size_t)c * 64];
    float run = 0.f;
#pragma unroll
    for (int c = 0; c < NC; ++c) {
      p[(size_t)c * 64] = run;
      run += x[c];
    }
  }
}

// ---------------- Pass C: per-chunk output via MFMA ----------------
// 4 waves; wave w owns row-tiles {w, 7-w}. Full-P build (one lgkm drain per m instead of 4
// per-strip drains). q/k fragments direct from global with q issued early and k 1-deep
// prefetched. v staged via coalesced transposed gather (no LDS scalar transpose).
__global__ __launch_bounds__(256) void pass_c(const float* __restrict__ q0,
                                              const float* __restrict__ q1,
                                              const float* __restrict__ k0,
                                              const float* __restrict__ k1,
                                              const float* __restrict__ v,
                                              const float* __restrict__ ws,
                                              float* __restrict__ out) {
  __shared__ __align__(16) unsigned short svT[64 * 136];   // vT[e][j]
  __shared__ __align__(16) unsigned short sST[64 * 72];    // S^T[e][d] staged per m
  __shared__ __align__(16) unsigned short sP[128 * 136];   // P[i][j] bf16 (wave-private rows)
  __shared__ float skpref[64];
  __shared__ float sden[128];

  int hh = blockIdx.x >> 5, c = blockIdx.x & 31;
  int t = threadIdx.x;
  int w = t >> 6, L = t & 63, g = L >> 4, cL = L & 15;
  size_t off = (size_t)hh * SEQ * DIM + (size_t)c * CHUNK * DIM;
  int rt0 = w, rt1 = 7 - w;                     // exactly one of rt0/rt1 is even

  gather_T<false>(v + off, svT, t);

  f32x4 accO[2][4];
#pragma unroll
  for (int a = 0; a < 2; ++a)
#pragma unroll
    for (int b = 0; b < 4; ++b) accO[a][b] = (f32x4){0.f, 0.f, 0.f, 0.f};
  float denfrag[2][4] = {};
  float denp[2] = {0.f, 0.f};

  const unsigned short* Sbase = (const unsigned short*)ws;

#pragma unroll
  for (int m = 0; m < 2; ++m) {
    const float* qp = (m ? q1 : q0) + off;
    const float* kp = (m ? k1 : k0) + off;
    const unsigned short* Sp = Sbase + (size_t)(m * 512 + hh * 32 + c) * 4096;
    const float* Kp = ws + KS_OFF + (size_t)(m * 512 + hh * 32 + c) * 64;

    // issue q loads early (pure global, latency hides under barrier + ST stage)
    float4 qa0[2][2], qa1[2][2];
#pragma unroll
    for (int ti = 0; ti < 2; ++ti) {
      int row = (ti ? rt1 : rt0) * 16 + cL;
#pragma unroll
      for (int h = 0; h < 2; ++h) {
        const float* qb = qp + (size_t)row * DIM + h * 32 + g * 8;
        qa0[ti][h] = *(const float4*)qb;
        qa1[ti][h] = *(const float4*)(qb + 4);
      }
    }

    if (m) __syncthreads();  // all inter-reads of sST/skpref (and m=0 sP reads) done

    // stage S^T (already bf16) rows stride 72, and ksum prefix
#pragma unroll
    for (int p2 = 0; p2 < 2; ++p2) {
      int idx = t + p2 * 256;                  // 512 x 16B covers 64x64 bf16
      *(s16x8*)&sST[(idx >> 3) * 72 + (idx & 7) * 8] = *(const s16x8*)&Sp[idx * 8];
    }
    if (t < 64) skpref[t] = Kp[t];
    __syncthreads();                           // covers svT (m=0) + sST + skpref

    // ksum-prefix fragment (same d-range for both row-tiles)
    float kpf[2][8];
#pragma unroll
    for (int h = 0; h < 2; ++h) {
      float4 c0 = *(const float4*)&skpref[h * 32 + g * 8];
      float4 c1 = *(const float4*)&skpref[h * 32 + g * 8 + 4];
      kpf[h][0] = c0.x; kpf[h][1] = c0.y; kpf[h][2] = c0.z; kpf[h][3] = c0.w;
      kpf[h][4] = c1.x; kpf[h][5] = c1.y; kpf[h][6] = c1.z; kpf[h][7] = c1.w;
    }

    // pack q A-frags; den partial with fp32 q
    s16x8 aq[2][2];
#pragma unroll
    for (int ti = 0; ti < 2; ++ti)
#pragma unroll
      for (int h = 0; h < 2; ++h) {
        float4 a0 = qa0[ti][h], a1 = qa1[ti][h];
        denp[ti] += a0.x * kpf[h][0] + a0.y * kpf[h][1] + a0.z * kpf[h][2] + a0.w * kpf[h][3]
                  + a1.x * kpf[h][4] + a1.y * kpf[h][5] + a1.z * kpf[h][6] + a1.w * kpf[h][7];
        aq[ti][h] = pack8(a0, a1);
      }

    // inter: O += q @ S_prefix
#pragma unroll
    for (int h = 0; h < 2; ++h)
#pragma unroll
      for (int et = 0; et < 4; ++et) {
        s16x8 bS = *(const s16x8*)&sST[(et * 16 + cL) * 72 + h * 32 + g * 8];
        accO[0][et] = __builtin_amdgcn_mfma_f32_16x16x32_bf16(aq[0][h], bS, accO[0][et], 0, 0, 0);
        accO[1][et] = __builtin_amdgcn_mfma_f32_16x16x32_bf16(aq[1][h], bS, accO[1][et], 0, 0, 0);
      }

    // QK^T -> full P in sP (wave-private rows), 1-deep k prefetch
    float4 kc0[2], kc1[2];
    {
      const float* kb = kp + (size_t)cL * DIM;   // jt = 0
#pragma unroll
      for (int h = 0; h < 2; ++h) {
        kc0[h] = *(const float4*)(kb + h * 32 + g * 8);
        kc1[h] = *(const float4*)(kb + h * 32 + g * 8 + 4);
      }
    }
    for (int jt = 0; jt <= rt1; ++jt) {
      float4 kn0[2], kn1[2];
      if (jt < rt1) {
        const float* kb = kp + (size_t)((jt + 1) * 16 + cL) * DIM;
#pragma unroll
        for (int h = 0; h < 2; ++h) {
          kn0[h] = *(const float4*)(kb + h * 32 + g * 8);
          kn1[h] = *(const float4*)(kb + h * 32 + g * 8 + 4);
        }
      }
      s16x8 bK0 = pack8(kc0[0], kc1[0]);
      s16x8 bK1 = pack8(kc0[1], kc1[1]);
#pragma unroll
      for (int ti = 0; ti < 2; ++ti) {
        int rt = ti ? rt1 : rt0;
        if (jt > rt) continue;                  // wave-uniform (only filters ti=0)
        f32x4 C = (f32x4){0.f, 0.f, 0.f, 0.f};
        C = __builtin_amdgcn_mfma_f32_16x16x32_bf16(aq[ti][0], bK0, C, 0, 0, 0);
        C = __builtin_amdgcn_mfma_f32_16x16x32_bf16(aq[ti][1], bK1, C, 0, 0, 0);
        if (jt == rt) {                         // diagonal: keep col<=row
#pragma unroll
          for (int r = 0; r < 4; ++r)
            if (cL > g * 4 + r) C[r] = 0.f;
        }
#pragma unroll
        for (int r = 0; r < 4; ++r) {
          denfrag[ti][r] += C[r];
          sP[(size_t)(rt * 16 + g * 4 + r) * 136 + jt * 16 + cL] = f2bf(C[r]);
        }
      }
#pragma unroll
      for (int h = 0; h < 2; ++h) { kc0[h] = kn0[h]; kc1[h] = kn1[h]; }
    }
    // zero-fill the (even rt, jt=rt+1) half-tile so the ks=rt/2 A-fragment is clean
    {
      int rte = (rt0 & 1) ? rt1 : rt0;
#pragma unroll
      for (int r = 0; r < 4; ++r)
        sP[(size_t)(rte * 16 + g * 4 + r) * 136 + (rte + 1) * 16 + cL] = 0;
    }

    asm volatile("s_waitcnt lgkmcnt(0)" ::: "memory");  // wave-private P rows visible

    // PV: O += P @ vT   (skip ks-blocks fully above the diagonal)
#pragma unroll
    for (int ks = 0; ks < 4; ++ks) {
      s16x8 bV[4];
#pragma unroll
      for (int et = 0; et < 4; ++et)
        bV[et] = *(const s16x8*)&svT[(et * 16 + cL) * 136 + ks * 32 + g * 8];
#pragma unroll
      for (int ti = 0; ti < 2; ++ti) {
        int rt = ti ? rt1 : rt0;
        if (ks > (rt >> 1)) continue;           // wave-uniform
        s16x8 aP = *(const s16x8*)&sP[(size_t)(rt * 16 + cL) * 136 + ks * 32 + g * 8];
#pragma unroll
        for (int et = 0; et < 4; ++et)
          accO[ti][et] = __builtin_amdgcn_mfma_f32_16x16x32_bf16(aP, bV[et], accO[ti][et], 0, 0, 0);
      }
    }
  }

  // reduce den over the 4 g-lanes (full d coverage), publish per row
#pragma unroll
  for (int ti = 0; ti < 2; ++ti) {
    denp[ti] += __shfl_xor(denp[ti], 16);
    denp[ti] += __shfl_xor(denp[ti], 32);
  }
  if (L < 16) {
    sden[rt0 * 16 + L] = denp[0];
    sden[rt1 * 16 + L] = denp[1];
  }
  __syncthreads();

  // finalize: butterfly intra rowsums over 16 col-lanes, scale, store
  float* op = out + off;
#pragma unroll
  for (int ti = 0; ti < 2; ++ti) {
    int rt = ti ? rt1 : rt0;
#pragma unroll
    for (int r = 0; r < 4; ++r) {
      float vs = denfrag[ti][r];
      vs += __shfl_xor(vs, 1);
      vs += __shfl_xor(vs, 2);
      vs += __shfl_xor(vs, 4);
      vs += __shfl_xor(vs, 8);
      int row = rt * 16 + g * 4 + r;
      float inv = 1.f / (sden[row] + vs + EPSV);
#pragma unroll
      for (int et = 0; et < 4; ++et)
        op[(size_t)row * 64 + et * 16 + cL] = accO[ti][et][r] * inv;
    }
  }
}

extern "C" void kernel_launch(void* const* d_in, const int* in_sizes, int n_in,
                              void* d_out, int out_size, void* d_ws, size_t ws_size,
                              hipStream_t stream) {
  const float* q  = (const float*)d_in[0];
  const float* k  = (const float*)d_in[1];
  const float* qr = (const float*)d_in[2];
  const float* kr = (const float*)d_in[3];
  const float* v  = (const float*)d_in[4];
  float* out = (float*)d_out;
  float* ws  = (float*)d_ws;

  hipLaunchKernelGGL(pass_a, dim3(1024), dim3(256), 0, stream, k, kr, v, ws);
  hipLaunchKernelGGL(pass_b, dim3(264), dim3(256), 0, stream, ws);
  hipLaunchKernelGGL(pass_c, dim3(512), dim3(256), 0, stream, q, qr, k, kr, v, ws, out);
}